// Round 3
// baseline (100.759 us; speedup 1.0000x reference)
//
#include <hip/hip_runtime.h>
#include <math.h>

#define N_ROWS 8192
#define HDIM   1024
#define KK     10
#define EPSF   1e-8f
#define NBLK   512

// VALU-pipe wave64 all-reduce via DPP (row_shr / row_bcast) — keeps the DS
// pipe idle (it was co-dominant with HBM when using ds_swizzle butterflies).
#define DPP_ADD(x, ctrl, rmask, bmask)                                        \
    x += __int_as_float(__builtin_amdgcn_update_dpp(                          \
        0, __float_as_int(x), ctrl, rmask, bmask, true))

__device__ __forceinline__ float wave_allreduce_add(float x) {
    DPP_ADD(x, 0x111, 0xf, 0xf);  // row_shr:1
    DPP_ADD(x, 0x112, 0xf, 0xf);  // row_shr:2
    DPP_ADD(x, 0x114, 0xf, 0xe);  // row_shr:4
    DPP_ADD(x, 0x118, 0xf, 0xc);  // row_shr:8
    DPP_ADD(x, 0x142, 0xa, 0xf);  // row_bcast:15
    DPP_ADD(x, 0x143, 0xc, 0xf);  // row_bcast:31
    return __int_as_float(__builtin_amdgcn_readlane(__float_as_int(x), 63));
}

// Single fused kernel: one wave per row (grid-stride, 4 rows/wave), centers
// register-resident (160 VGPR -> 2 waves/SIMD; 8 waves/CU keep 32 KB/CU of
// loads in flight >> 9 KB BW*latency product). Final reduction by the LAST
// block to finish (device-scope counter), eliminating the tail kernel launch.
__global__ __launch_bounds__(256, 2)
void knife_fused(const float* __restrict__ x,
                 const float* __restrict__ centers,
                 const float* __restrict__ weights,
                 const float* __restrict__ scales,
                 float* __restrict__ partials,
                 unsigned int* __restrict__ counter,
                 float* __restrict__ out) {
    const int lane = threadIdx.x & 63;
    const int wid  = threadIdx.x >> 6;
    const int gwave  = blockIdx.x * 4 + wid;   // 2048 waves
    const int nwaves = NBLK * 4;
    const int ROWS   = N_ROWS / 2048;          // 4 rows per wave

    // Centers: lane owns float4 positions lane + 64*j, j=0..3 (160 VGPRs)
    const float4* c4 = (const float4*)centers;
    float4 c[KK][4];
#pragma unroll
    for (int k = 0; k < KK; ++k)
#pragma unroll
        for (int j = 0; j < 4; ++j)
            c[k][j] = c4[k * (HDIM / 4) + lane + 64 * j];

    // ||c_k||^2 (wave-uniform -> SGPR via readlane)
    float csq[KK];
#pragma unroll
    for (int k = 0; k < KK; ++k) {
        float s = 0.f;
#pragma unroll
        for (int j = 0; j < 4; ++j) {
            float4 v = c[k][j];
            s += v.x * v.x + v.y * v.y + v.z * v.z + v.w * v.w;
        }
        csq[k] = wave_allreduce_add(s);
    }

    float w[KK], inv2s2[KK];
#pragma unroll
    for (int k = 0; k < KK; ++k) {
        w[k] = weights[k];
        float sc = scales[k];
        inv2s2[k] = 1.0f / (2.0f * sc * sc);
    }

    const float4* x4 = (const float4*)x;
    float logsum = 0.f;

    int row = gwave;
    float4 xv[4], nx[4];
#pragma unroll
    for (int j = 0; j < 4; ++j)
        xv[j] = x4[((size_t)row << 8) + lane + 64 * j];

#pragma unroll
    for (int i = 0; i < 4; ++i) {   // ROWS == 4
        const int nrow = row + nwaves;
        // Prefetch next row before the dependent FMA/reduce/exp chain.
        if (i + 1 < ROWS) {
#pragma unroll
            for (int j = 0; j < 4; ++j)
                nx[j] = x4[((size_t)nrow << 8) + lane + 64 * j];
        }

        float acc[KK + 1];
#pragma unroll
        for (int k = 0; k <= KK; ++k) acc[k] = 0.f;
#pragma unroll
        for (int j = 0; j < 4; ++j) {
            float4 v = xv[j];
            acc[KK] += v.x * v.x + v.y * v.y + v.z * v.z + v.w * v.w;
#pragma unroll
            for (int k = 0; k < KK; ++k) {
                float4 cv = c[k][j];
                acc[k] += v.x * cv.x + v.y * cv.y + v.z * cv.z + v.w * cv.w;
            }
        }

        float xsq = wave_allreduce_add(acc[KK]);
        float density = 0.f;
#pragma unroll
        for (int k = 0; k < KK; ++k) {
            float dot = wave_allreduce_add(acc[k]);
            float d = fmaxf(xsq + csq[k] - 2.0f * dot, 0.0f);
            density += w[k] * __expf(-d * inv2s2[k]);
        }
        logsum += __logf(density + EPSF);

        if (i + 1 < ROWS) {
#pragma unroll
            for (int j = 0; j < 4; ++j) xv[j] = nx[j];
            row = nrow;
        }
    }

    // Block partial -> global (agent scope so other XCDs see it), then
    // last-arriving block does the grid reduction. Counter was memset to 0
    // by a 4-byte hipMemsetAsync node (no reliance on 0xAA poison base).
    __shared__ float red1[4];
    __shared__ float flag;
    if (lane == 0) red1[wid] = logsum;
    __syncthreads();
    if (threadIdx.x == 0) {
        float v = red1[0] + red1[1] + red1[2] + red1[3];
        __hip_atomic_store(&partials[blockIdx.x], v,
                           __ATOMIC_RELEASE, __HIP_MEMORY_SCOPE_AGENT);
        unsigned int old = __hip_atomic_fetch_add(
            counter, 1u, __ATOMIC_ACQ_REL, __HIP_MEMORY_SCOPE_AGENT);
        flag = (old == NBLK - 1) ? 1.f : 0.f;
    }
    __syncthreads();
    if (flag != 0.f) {
        // Last block: reduce all 512 partials. Agent-scope atomic loads
        // bypass potentially-stale per-XCD L2 lines.
        int t = threadIdx.x;
        float s = __hip_atomic_load(&partials[t], __ATOMIC_ACQUIRE,
                                    __HIP_MEMORY_SCOPE_AGENT)
                + __hip_atomic_load(&partials[t + 256], __ATOMIC_ACQUIRE,
                                    __HIP_MEMORY_SCOPE_AGENT);
        s = wave_allreduce_add(s);
        __shared__ float red2[4];
        if ((t & 63) == 0) red2[t >> 6] = s;
        __syncthreads();
        if (t == 0) {
            float total = red2[0] + red2[1] + red2[2] + red2[3];
            float h = -total / (float)N_ROWS;   // h_entropy
            out[0] = h;           // entropy_loss (BETA=1)
            out[1] = h * h;       // target_entropy_loss (TARGET=0)
            out[2] = h + h * h;   // total_loss
            out[3] = h;           // h_entropy
        }
    }
}

extern "C" void kernel_launch(void* const* d_in, const int* in_sizes, int n_in,
                              void* d_out, int out_size, void* d_ws, size_t ws_size,
                              hipStream_t stream) {
    const float* x       = (const float*)d_in[0];
    const float* centers = (const float*)d_in[1];
    const float* weights = (const float*)d_in[2];
    const float* scales  = (const float*)d_in[3];
    float* out      = (float*)d_out;
    float* partials = (float*)d_ws;                       // 512 floats
    unsigned int* counter = (unsigned int*)((char*)d_ws + NBLK * sizeof(float));

    // Deterministic counter init every call (graph-capturable async memset).
    hipMemsetAsync(counter, 0, sizeof(unsigned int), stream);
    knife_fused<<<NBLK, 256, 0, stream>>>(x, centers, weights, scales,
                                          partials, counter, out);
}

// Round 4
// 87.093 us; speedup vs baseline: 1.1569x; 1.1569x over previous
//
#include <hip/hip_runtime.h>
#include <math.h>

#define N_ROWS 8192
#define HDIM   1024
#define KK     10
#define EPSF   1e-8f
#define NBLK   256
#define TPB    512              // 8 waves/block
#define WPB    (TPB / 64)
#define RPW    4                // rows per wave (register-blocked)

// VALU-pipe wave64 all-reduce via DPP (row_shr / row_bcast); DS pipe stays
// reserved for center reads.
#define DPP_ADD(x, ctrl, rmask, bmask)                                        \
    x += __int_as_float(__builtin_amdgcn_update_dpp(                          \
        0, __float_as_int(x), ctrl, rmask, bmask, true))

__device__ __forceinline__ float wave_allreduce_add(float x) {
    DPP_ADD(x, 0x111, 0xf, 0xf);  // row_shr:1
    DPP_ADD(x, 0x112, 0xf, 0xf);  // row_shr:2
    DPP_ADD(x, 0x114, 0xf, 0xe);  // row_shr:4
    DPP_ADD(x, 0x118, 0xf, 0xc);  // row_shr:8
    DPP_ADD(x, 0x142, 0xa, 0xf);  // row_bcast:15
    DPP_ADD(x, 0x143, 0xc, 0xf);  // row_bcast:31
    return __int_as_float(__builtin_amdgcn_readlane(__float_as_int(x), 63));
}

// Centers staged to LDS once per block (40 KB); each wave register-blocks 4
// consecutive rows so every ds_read_b128 of a center fragment feeds 4 rows.
// R3 evidence: VGPR_Count=104 proved the compiler would NOT keep a
// float4[10][4] center array in registers (it reloaded from global per row,
// latency-bound at 370 GB/s). LDS makes the reuse explicit and predictable.
__global__ __launch_bounds__(TPB, 2)
void knife_main(const float* __restrict__ x,
                const float* __restrict__ centers,
                const float* __restrict__ weights,
                const float* __restrict__ scales,
                float* __restrict__ partials) {
    const int lane = threadIdx.x & 63;
    const int wid  = threadIdx.x >> 6;

    __shared__ float4 cs[KK * (HDIM / 4)];   // 40960 B

    // Stage centers: coalesced thread-stride copy (b128 in / b128 out).
    const float4* c4 = (const float4*)centers;
    for (int i = threadIdx.x; i < KK * (HDIM / 4); i += TPB)
        cs[i] = c4[i];

    // weights/scales: uniform scalar loads
    float w[KK], inv2s2[KK];
#pragma unroll
    for (int k = 0; k < KK; ++k) {
        w[k] = weights[k];
        float sc = scales[k];
        inv2s2[k] = 1.0f / (2.0f * sc * sc);
    }

    // Issue the wave's 4 rows of x (16 x b128, 16 KB in flight) BEFORE
    // touching LDS so HBM latency overlaps the barrier + csq work.
    const int g  = blockIdx.x * WPB + wid;       // 0..2047
    const int r0 = g * RPW;                      // 4 consecutive rows
    const float4* xr = (const float4*)x + ((size_t)r0 << 8);
    float4 xv[RPW][4];
#pragma unroll
    for (int r = 0; r < RPW; ++r)
#pragma unroll
        for (int j = 0; j < 4; ++j)
            xv[r][j] = xr[(size_t)r * 256 + lane + 64 * j];

    __syncthreads();

    // ||c_k||^2 per wave from LDS (cheap, wave-uniform -> SGPR)
    float csq[KK];
#pragma unroll
    for (int k = 0; k < KK; ++k) {
        float s = 0.f;
#pragma unroll
        for (int j = 0; j < 4; ++j) {
            float4 v = cs[k * 256 + lane + 64 * j];
            s += v.x * v.x + v.y * v.y + v.z * v.z + v.w * v.w;
        }
        csq[k] = wave_allreduce_add(s);
    }

    // Main FMA: read each center fragment once, use it for 4 rows.
    float acc[RPW][KK + 1];
#pragma unroll
    for (int r = 0; r < RPW; ++r)
#pragma unroll
        for (int k = 0; k <= KK; ++k) acc[r][k] = 0.f;

#pragma unroll
    for (int j = 0; j < 4; ++j) {
#pragma unroll
        for (int r = 0; r < RPW; ++r) {
            float4 v = xv[r][j];
            acc[r][KK] += v.x * v.x + v.y * v.y + v.z * v.z + v.w * v.w;
        }
#pragma unroll
        for (int k = 0; k < KK; ++k) {
            float4 cv = cs[k * 256 + lane + 64 * j];   // ds_read_b128, x4 reuse
#pragma unroll
            for (int r = 0; r < RPW; ++r) {
                float4 v = xv[r][j];
                acc[r][k] += v.x * cv.x + v.y * cv.y + v.z * cv.z + v.w * cv.w;
            }
        }
    }

    // 44 independent DPP chains pipeline on the VALU; then density/log.
    float logsum = 0.f;
#pragma unroll
    for (int r = 0; r < RPW; ++r) {
        float xsq = wave_allreduce_add(acc[r][KK]);
        float density = 0.f;
#pragma unroll
        for (int k = 0; k < KK; ++k) {
            float dot = wave_allreduce_add(acc[r][k]);
            float d = fmaxf(xsq + csq[k] - 2.0f * dot, 0.0f);
            density += w[k] * __expf(-d * inv2s2[k]);
        }
        logsum += __logf(density + EPSF);
    }

    __shared__ float red[WPB];
    if (lane == 0) red[wid] = logsum;
    __syncthreads();
    if (threadIdx.x == 0) {
        float t = 0.f;
#pragma unroll
        for (int i = 0; i < WPB; ++i) t += red[i];
        partials[blockIdx.x] = t;
    }
}

// Deterministic final reduction of 256 block partials + output assembly.
__global__ __launch_bounds__(256)
void knife_final(const float* __restrict__ partials, float* __restrict__ out) {
    __shared__ float red[4];
    int t = threadIdx.x;
    float s = partials[t];
    s = wave_allreduce_add(s);
    if ((t & 63) == 0) red[t >> 6] = s;
    __syncthreads();
    if (t == 0) {
        float total = red[0] + red[1] + red[2] + red[3];
        float h = -total / (float)N_ROWS;   // h_entropy
        out[0] = h;           // entropy_loss (BETA=1)
        out[1] = h * h;       // target_entropy_loss (TARGET=0)
        out[2] = h + h * h;   // total_loss
        out[3] = h;           // h_entropy
    }
}

extern "C" void kernel_launch(void* const* d_in, const int* in_sizes, int n_in,
                              void* d_out, int out_size, void* d_ws, size_t ws_size,
                              hipStream_t stream) {
    const float* x       = (const float*)d_in[0];
    const float* centers = (const float*)d_in[1];
    const float* weights = (const float*)d_in[2];
    const float* scales  = (const float*)d_in[3];
    float* out      = (float*)d_out;
    float* partials = (float*)d_ws;   // 256 floats

    knife_main<<<NBLK, TPB, 0, stream>>>(x, centers, weights, scales, partials);
    knife_final<<<1, 256, 0, stream>>>(partials, out);
}